// Round 4
// baseline (579.146 us; speedup 1.0000x reference)
//
#include <hip/hip_runtime.h>
#include <hip/hip_bf16.h>

#define IN_CHN 256
#define OUT_CHN 256
#define REL_DIM 1536
#define HIDN 512
#define ECAP 384

using short8 = __attribute__((ext_vector_type(8))) short;
using f32x4  = __attribute__((ext_vector_type(4))) float;

__device__ __forceinline__ float bf2f(short s) {
    union { unsigned u; float f; } v;
    v.u = ((unsigned)(unsigned short)s) << 16;
    return v.f;
}
__device__ __forceinline__ unsigned cvt_pk_bf16(float a, float b) {
    unsigned r;
    asm("v_cvt_pk_bf16_f32 %0, %1, %2" : "=v"(r) : "v"(a), "v"(b));
    return r;
}
__device__ __forceinline__ unsigned short f2bf_s(float f) {
    union { float f; unsigned u; } v; v.f = f;
    unsigned u = v.u + 0x7FFFu + ((v.u >> 16) & 1u);
    return (unsigned short)(u >> 16);
}

// ---------------- prep: transpose+cast weights to bf16 ----------------
__global__ void k_prep_w(const float* __restrict__ W1, const float* __restrict__ Ws,
                         const float* __restrict__ W2,
                         unsigned short* __restrict__ Bt, unsigned short* __restrict__ W2t,
                         unsigned short* __restrict__ Wst)
{
    int idx = blockIdx.x * 256 + threadIdx.x;
    const int n1 = HIDN * IN_CHN;
    const int n2 = OUT_CHN * HIDN;
    const int n3 = OUT_CHN * IN_CHN;
    if (idx < n1) {
        int j = idx >> 8, k = idx & 255;
        Bt[idx] = f2bf_s(W1[(size_t)k * HIDN + j]);
    } else if (idx < n1 + n2) {
        int t = idx - n1;
        int j = t >> 9, k = t & 511;
        W2t[t] = f2bf_s(W2[(size_t)k * OUT_CHN + j]);
    } else if (idx < n1 + n2 + n3) {
        int t = idx - n1 - n2;
        int j = t >> 8, k = t & 255;
        Wst[t] = f2bf_s(Ws[(size_t)k * OUT_CHN + j]);
    }
}

// ---------------- R[r] = rel[r] @ W1_bot + b1 (bf16 out) ----------------
__global__ __launch_bounds__(512) void k_rel(const float* __restrict__ rel,
                                             const float* __restrict__ W1,
                                             const float* __restrict__ b1,
                                             unsigned short* __restrict__ Rb)
{
    __shared__ float s[REL_DIM];
    const int r = blockIdx.x;
    for (int i = threadIdx.x; i < REL_DIM; i += 512)
        s[i] = rel[(size_t)r * REL_DIM + i];
    __syncthreads();
    const int j = threadIdx.x;
    float acc = b1[j];
    const float* wp = W1 + (size_t)IN_CHN * HIDN + j;
#pragma unroll 8
    for (int k = 0; k < REL_DIM; ++k)
        acc = fmaf(s[k], wp[(size_t)k * HIDN], acc);
    Rb[r * HIDN + j] = f2bf_s(acc);
}

// ---------------- node GEMM: X1 = bf16(x) @ Bt^T ----------------
__global__ __launch_bounds__(512) void k_node(const float* __restrict__ x,
                                              const unsigned short* __restrict__ Bt,
                                              unsigned short* __restrict__ X1, int N)
{
    const int row0 = blockIdx.x * 64;
    const int tid = threadIdx.x;
    const int w = tid >> 6, l = tid & 63;
    const int l15 = l & 15, lg = l >> 4;
    const int colw = w * 64;

    const float* ap[4];
#pragma unroll
    for (int rf = 0; rf < 4; ++rf) {
        int row = row0 + 16 * rf + l15;
        if (row >= N) row = N - 1;
        ap[rf] = x + (size_t)row * IN_CHN + 8 * lg;
    }
    const unsigned short* bp[4];
#pragma unroll
    for (int cf = 0; cf < 4; ++cf)
        bp[cf] = Bt + (size_t)(colw + 16 * cf + l15) * IN_CHN + 8 * lg;

    f32x4 acc[4][4] = {};
    for (int k0 = 0; k0 < IN_CHN; k0 += 32) {
        short8 a[4], b[4];
#pragma unroll
        for (int rf = 0; rf < 4; ++rf) {
            float4 lo = *(const float4*)(ap[rf] + k0);
            float4 hi = *(const float4*)(ap[rf] + k0 + 4);
            union { short8 s; unsigned u[4]; } pk;
            pk.u[0] = cvt_pk_bf16(lo.x, lo.y);
            pk.u[1] = cvt_pk_bf16(lo.z, lo.w);
            pk.u[2] = cvt_pk_bf16(hi.x, hi.y);
            pk.u[3] = cvt_pk_bf16(hi.z, hi.w);
            a[rf] = pk.s;
        }
#pragma unroll
        for (int cf = 0; cf < 4; ++cf)
            b[cf] = *(const short8*)(bp[cf] + k0);
#pragma unroll
        for (int rf = 0; rf < 4; ++rf)
#pragma unroll
            for (int cf = 0; cf < 4; ++cf)
                acc[rf][cf] = __builtin_amdgcn_mfma_f32_16x16x32_bf16(a[rf], b[cf], acc[rf][cf], 0, 0, 0);
    }
#pragma unroll
    for (int rf = 0; rf < 4; ++rf) {
#pragma unroll
        for (int cf = 0; cf < 4; ++cf) {
            int col = colw + 16 * cf + l15;
#pragma unroll
            for (int r = 0; r < 4; ++r) {
                int row = row0 + 16 * rf + 4 * lg + r;
                if (row >= N) continue;
                X1[(size_t)row * HIDN + col] = f2bf_s(acc[rf][cf][r]);
            }
        }
    }
}

// ---------------- CSR build ----------------
__global__ void k_hist(const int* __restrict__ ei, int* __restrict__ cnt, int E)
{
    int e = blockIdx.x * 256 + threadIdx.x;
    if (e < E) atomicAdd(&cnt[ei[E + e]], 1);
}

__global__ __launch_bounds__(512) void k_scan1(const int* __restrict__ cnt, int* __restrict__ offs,
                                               int* __restrict__ bsum, int N)
{
    __shared__ int s[512];
    int t = threadIdx.x;
    int i = blockIdx.x * 512 + t;
    int v = (i < N) ? cnt[i] : 0;
    s[t] = v;
    __syncthreads();
    for (int d = 1; d < 512; d <<= 1) {
        int a = (t >= d) ? s[t - d] : 0;
        __syncthreads();
        s[t] += a;
        __syncthreads();
    }
    if (i < N) offs[i] = s[t] - v;
    if (t == 511) bsum[blockIdx.x] = s[511];
}

__global__ __launch_bounds__(512) void k_scan2(int* __restrict__ bsum, int NB)
{
    __shared__ int s[512];
    int t = threadIdx.x;
    if (t < NB) s[t] = bsum[t];
    __syncthreads();
    if (t == 0) {
        int run = 0;
        for (int j = 0; j < NB; ++j) { int v = s[j]; s[j] = run; run += v; }
    }
    __syncthreads();
    if (t < NB) bsum[t] = s[t];
}

__global__ void k_scan3(int* __restrict__ offs, const int* __restrict__ bsum,
                        int* __restrict__ cursor, int N, int E)
{
    int i = blockIdx.x * 256 + threadIdx.x;
    if (i < N) {
        int v = offs[i] + bsum[i >> 9];
        offs[i] = v;
        cursor[i] = v;
    }
    if (i == 0) offs[N] = E;
}

__global__ void k_scatter(const int* __restrict__ ei, const int* __restrict__ et,
                          int* __restrict__ cursor, int* __restrict__ eperm, int E)
{
    int e = blockIdx.x * 256 + threadIdx.x;
    if (e < E) {
        int d = ei[E + e];
        int pos = atomicAdd(&cursor[d], 1);
        eperm[pos] = ei[e] | (et[e] << 20);   // src | etype<<20
    }
}

// ---------------- fused: gather-agg H -> LDS, GEMM @W2 + x@Ws, +deg*b2+bs, LN, ReLU ----------------
// grid ceil(N/32); block 256 (4 waves). LDS ~35.4 KB -> 4 blocks/CU.
// Phase 1: offs+eperm staged in LDS; each wave runs 2 passes of 4 concurrent node chains.
__global__ __launch_bounds__(256) void k_agg(const int* __restrict__ offs,
                                             const int* __restrict__ eperm,
                                             const unsigned short* __restrict__ X1,
                                             const unsigned short* __restrict__ Rb,
                                             const unsigned short* __restrict__ W2t,
                                             const unsigned short* __restrict__ Wst,
                                             const float* __restrict__ x,
                                             const float* __restrict__ b2,
                                             const float* __restrict__ bs,
                                             const float* __restrict__ gamma,
                                             const float* __restrict__ beta,
                                             float* __restrict__ out, int N)
{
    __shared__ unsigned short shH[32 * HIDN];   // XOR-swizzled: (l*8) ^ ((n&7)<<3)
    __shared__ int s_offs[33];
    __shared__ int s_ep[ECAP];
    __shared__ float sred[4][32], sqred[4][32];
    const int tid = threadIdx.x;
    const int w = tid >> 6, l = tid & 63;
    const int l15 = l & 15, lg = l >> 4;
    const int row0 = blockIdx.x * 32;

    // ---- stage CSR slice: offsets then contiguous eperm span ----
    if (tid < 33) {
        int g = row0 + tid;
        if (g > N) g = N;
        s_offs[tid] = offs[g];
    }
    __syncthreads();
    const int e0 = s_offs[0];
    const int espan = s_offs[32] - e0;
    for (int j = tid; j < espan && j < ECAP; j += 256)
        s_ep[j] = eperm[e0 + j];
    __syncthreads();

    // ---- phase 1: 2 passes x 4 concurrent per-node gather chains per wave ----
    for (int pass = 0; pass < 2; ++pass) {
        const int nb = w * 8 + pass * 4;
        int oc[4], oe[4];
#pragma unroll
        for (int n = 0; n < 4; ++n) { oc[n] = s_offs[nb + n]; oe[n] = s_offs[nb + n + 1]; }
        float a[4][8] = {};
        int tmax = max(max(oe[0] - oc[0], oe[1] - oc[1]), max(oe[2] - oc[2], oe[3] - oc[3]));
        for (int t = 0; t < tmax; ++t) {
            int pv[4];
            short8 xa[4], ra[4];
#pragma unroll
            for (int n = 0; n < 4; ++n)
                if (oc[n] + t < oe[n]) {
                    int idx = oc[n] + t - e0;
                    pv[n] = (idx < ECAP) ? s_ep[idx] : eperm[e0 + idx];
                }
#pragma unroll
            for (int n = 0; n < 4; ++n)
                if (oc[n] + t < oe[n]) {
                    xa[n] = *(const short8*)(X1 + (size_t)(pv[n] & 0xFFFFF) * HIDN + l * 8);
                    ra[n] = *(const short8*)(Rb + (pv[n] >> 20) * HIDN + l * 8);
                }
#pragma unroll
            for (int n = 0; n < 4; ++n)
                if (oc[n] + t < oe[n])
#pragma unroll
                    for (int j = 0; j < 8; ++j)
                        a[n][j] += fmaxf(bf2f(xa[n][j]) + bf2f(ra[n][j]), 0.f);
        }
#pragma unroll
        for (int n = 0; n < 4; ++n) {
            int node = nb + n;
            union { short8 s; unsigned u[4]; } pk;
            pk.u[0] = cvt_pk_bf16(a[n][0], a[n][1]);
            pk.u[1] = cvt_pk_bf16(a[n][2], a[n][3]);
            pk.u[2] = cvt_pk_bf16(a[n][4], a[n][5]);
            pk.u[3] = cvt_pk_bf16(a[n][6], a[n][7]);
            *(short8*)(shH + node * HIDN + ((l * 8) ^ ((node & 7) << 3))) = pk.s;
        }
    }
    __syncthreads();

    // ---- phase 2a: H @ W2t, K=512, A from LDS ----
    const int colw = w * 64;
    const unsigned short* bp[4];
#pragma unroll
    for (int cf = 0; cf < 4; ++cf)
        bp[cf] = W2t + (size_t)(colw + 16 * cf + l15) * HIDN + 8 * lg;
    int arow[2], axor[2];
#pragma unroll
    for (int rf = 0; rf < 2; ++rf) {
        int rr = 16 * rf + l15;
        arow[rf] = rr * HIDN;
        axor[rf] = (rr & 7) << 3;
    }
    f32x4 acc[2][4] = {};
    for (int k0 = 0; k0 < HIDN; k0 += 32) {
        short8 a[2], b[4];
#pragma unroll
        for (int rf = 0; rf < 2; ++rf)
            a[rf] = *(const short8*)(shH + arow[rf] + ((k0 + 8 * lg) ^ axor[rf]));
#pragma unroll
        for (int cf = 0; cf < 4; ++cf)
            b[cf] = *(const short8*)(bp[cf] + k0);
#pragma unroll
        for (int rf = 0; rf < 2; ++rf)
#pragma unroll
            for (int cf = 0; cf < 4; ++cf)
                acc[rf][cf] = __builtin_amdgcn_mfma_f32_16x16x32_bf16(a[rf], b[cf], acc[rf][cf], 0, 0, 0);
    }

    // ---- phase 2b: + x @ Wst, K=256, A direct from global (rows contiguous) ----
    const float* xp[2];
#pragma unroll
    for (int rf = 0; rf < 2; ++rf) {
        int row = row0 + 16 * rf + l15;
        if (row >= N) row = N - 1;
        xp[rf] = x + (size_t)row * IN_CHN + 8 * lg;
    }
    const unsigned short* sp[4];
#pragma unroll
    for (int cf = 0; cf < 4; ++cf)
        sp[cf] = Wst + (size_t)(colw + 16 * cf + l15) * IN_CHN + 8 * lg;
    for (int k0 = 0; k0 < IN_CHN; k0 += 32) {
        short8 a[2], b[4];
#pragma unroll
        for (int rf = 0; rf < 2; ++rf) {
            float4 lo = *(const float4*)(xp[rf] + k0);
            float4 hi = *(const float4*)(xp[rf] + k0 + 4);
            union { short8 s; unsigned u[4]; } pk;
            pk.u[0] = cvt_pk_bf16(lo.x, lo.y);
            pk.u[1] = cvt_pk_bf16(lo.z, lo.w);
            pk.u[2] = cvt_pk_bf16(hi.x, hi.y);
            pk.u[3] = cvt_pk_bf16(hi.z, hi.w);
            a[rf] = pk.s;
        }
#pragma unroll
        for (int cf = 0; cf < 4; ++cf)
            b[cf] = *(const short8*)(sp[cf] + k0);
#pragma unroll
        for (int rf = 0; rf < 2; ++rf)
#pragma unroll
            for (int cf = 0; cf < 4; ++cf)
                acc[rf][cf] = __builtin_amdgcn_mfma_f32_16x16x32_bf16(a[rf], b[cf], acc[rf][cf], 0, 0, 0);
    }

    // ---- epilogue: + deg*b2 + bs, LayerNorm over 256 cols, ReLU ----
    float b2v[4], bsv[4], gv[4], bv[4];
#pragma unroll
    for (int cf = 0; cf < 4; ++cf) {
        int col = colw + 16 * cf + l15;
        b2v[cf] = b2[col]; bsv[cf] = bs[col]; gv[cf] = gamma[col]; bv[cf] = beta[col];
    }
#pragma unroll
    for (int rf = 0; rf < 2; ++rf) {
#pragma unroll
        for (int r = 0; r < 4; ++r) {
            int row = 16 * rf + 4 * lg + r;
            float dg = (float)(s_offs[row + 1] - s_offs[row]);
            float s = 0.f, sq = 0.f;
#pragma unroll
            for (int cf = 0; cf < 4; ++cf) {
                float v = acc[rf][cf][r] + dg * b2v[cf] + bsv[cf];
                acc[rf][cf][r] = v;
                s += v; sq += v * v;
            }
#pragma unroll
            for (int o = 8; o > 0; o >>= 1) {
                s  += __shfl_xor(s, o);
                sq += __shfl_xor(sq, o);
            }
            if (l15 == 0) { sred[w][row] = s; sqred[w][row] = sq; }
        }
    }
    __syncthreads();
#pragma unroll
    for (int rf = 0; rf < 2; ++rf) {
#pragma unroll
        for (int r = 0; r < 4; ++r) {
            int row = 16 * rf + 4 * lg + r;
            int g = row0 + row;
            if (g >= N) continue;
            float tot  = sred[0][row] + sred[1][row] + sred[2][row] + sred[3][row];
            float totq = sqred[0][row] + sqred[1][row] + sqred[2][row] + sqred[3][row];
            float mu = tot * (1.f / OUT_CHN);
            float var = totq * (1.f / OUT_CHN) - mu * mu;
            float rstd = rsqrtf(var + 1e-5f);
#pragma unroll
            for (int cf = 0; cf < 4; ++cf) {
                int col = colw + 16 * cf + l15;
                float v = (acc[rf][cf][r] - mu) * rstd * gv[cf] + bv[cf];
                out[(size_t)g * OUT_CHN + col] = fmaxf(v, 0.f);
            }
        }
    }
}

extern "C" void kernel_launch(void* const* d_in, const int* in_sizes, int n_in,
                              void* d_out, int out_size, void* d_ws, size_t ws_size,
                              hipStream_t stream)
{
    const float* x     = (const float*)d_in[0];
    const int*   ei    = (const int*)d_in[1];
    const int*   etype = (const int*)d_in[2];
    const float* rel   = (const float*)d_in[3];
    const float* W1    = (const float*)d_in[4];
    const float* b1    = (const float*)d_in[5];
    const float* W2    = (const float*)d_in[6];
    const float* b2    = (const float*)d_in[7];
    const float* Ws    = (const float*)d_in[8];
    const float* bs    = (const float*)d_in[9];
    const float* gamma = (const float*)d_in[10];
    const float* beta  = (const float*)d_in[11];

    const int N  = in_sizes[0] / IN_CHN;
    const int E  = in_sizes[2];
    const int NR = in_sizes[3] / REL_DIM;
    float* outp = (float*)d_out;

    char* wsp = (char*)d_ws;
    auto carve = [&](size_t bytes) { char* p = wsp; wsp += (bytes + 255) & ~(size_t)255; return p; };
    unsigned short* X1  = (unsigned short*)carve((size_t)N * HIDN * 2);
    unsigned short* Rb  = (unsigned short*)carve((size_t)NR * HIDN * 2);
    unsigned short* Bt  = (unsigned short*)carve((size_t)HIDN * IN_CHN * 2);
    unsigned short* W2t = (unsigned short*)carve((size_t)OUT_CHN * HIDN * 2);
    unsigned short* Wst = (unsigned short*)carve((size_t)OUT_CHN * IN_CHN * 2);
    int* offs  = (int*)carve(((size_t)N + 1) * 4);
    int* cnt   = (int*)carve((size_t)N * 4);
    int* bsum  = (int*)carve(512 * 4);
    int* eperm = (int*)carve((size_t)E * 4);

    hipMemsetAsync(cnt, 0, (size_t)N * 4, stream);

    const int prep_total = HIDN * IN_CHN + OUT_CHN * HIDN + OUT_CHN * IN_CHN;
    k_prep_w<<<dim3((prep_total + 255) / 256), dim3(256), 0, stream>>>(W1, Ws, W2, Bt, W2t, Wst);
    k_rel<<<dim3(NR), dim3(512), 0, stream>>>(rel, W1, b1, Rb);
    k_node<<<dim3((N + 63) / 64), dim3(512), 0, stream>>>(x, Bt, X1, N);
    k_hist<<<dim3((E + 255) / 256), dim3(256), 0, stream>>>(ei, cnt, E);
    int NB = (N + 511) / 512;
    k_scan1<<<dim3(NB), dim3(512), 0, stream>>>(cnt, offs, bsum, N);
    k_scan2<<<dim3(1), dim3(512), 0, stream>>>(bsum, NB);
    k_scan3<<<dim3((N + 255) / 256), dim3(256), 0, stream>>>(offs, bsum, cnt, N, E);
    k_scatter<<<dim3((E + 255) / 256), dim3(256), 0, stream>>>(ei, etype, cnt, eperm, E);
    k_agg<<<dim3((N + 31) / 32), dim3(256), 0, stream>>>(offs, eperm, X1, Rb, W2t, Wst, x,
                                                         b2, bs, gamma, beta, outp, N);
}